// Round 8
// baseline (266.283 us; speedup 1.0000x reference)
//
#include <hip/hip_runtime.h>

#define B_ 4096
#define C_ 64
#define F_ 128
#define KP 136                       // padded K stride (bf16) -> 2-way banks max
#define PLANE_E (F_ * KP)            // 17408 u16
#define LAYER_E (2 * PLANE_E)        // hi+lo planes per layer
#define GRP 32                       // batches per MLP group
#define NGRP (B_ / GRP)              // 128 MLP blocks
#define NPREP 32                     // prep stripe blocks

typedef __attribute__((ext_vector_type(8))) short short8;
typedef __attribute__((ext_vector_type(4))) float f32x4;

__device__ __forceinline__ unsigned short bf16_trunc(float f) {
    union { float f; unsigned u; } v; v.f = f;
    return (unsigned short)(v.u >> 16);
}
__device__ __forceinline__ float bf16_tof(unsigned short h) {
    union { unsigned u; float f; } v; v.u = ((unsigned)h) << 16;
    return v.f;
}

struct Flags { int prep; int cnt[NGRP]; };

// ---------------------------------------------------------------------------
// One kernel, two roles.
//  blocks [0,4096): stream mean of batch b -> ebar; release-add cnt[b/32].
//                   blocks 0-31 first prep one W stripe (transpose + bf16
//                   hi/lo split) -> wprep; release-add prep counter.
//  blocks [4096, 4224): MLP group g: spin until prep==32 && cnt[g]==32,
//                   acquire, then 4-layer split-bf16 MFMA MLP for 32 batches.
//                   B-fragments straight from global wprep (L2/L3-hot);
//                   LDS holds only x (17.4 KB) so stream occupancy survives.
// ---------------------------------------------------------------------------
__global__ __launch_bounds__(256, 4) void fused_all(
    const float* __restrict__ emb,
    const float* __restrict__ W0, const float* __restrict__ b0,
    const float* __restrict__ W1, const float* __restrict__ b1,
    const float* __restrict__ W2, const float* __restrict__ b2,
    const float* __restrict__ Wr, const float* __restrict__ br,
    float* __restrict__ ebar, unsigned short* __restrict__ wprep,
    Flags* __restrict__ flags, float* __restrict__ out)
{
    __shared__ __align__(16) char smraw[2 * GRP * KP * 2];   // 17408 B

    const int b = blockIdx.x;
    const int t = threadIdx.x;

    if (b < B_) {
        // ================= STREAM ROLE =================
        float4* part = (float4*)smraw;           // [8][32] = 4 KB
        float*  tile = (float*)(smraw + 4096);   // [128*17] = 8704 B

        if (b < NPREP) {
            // ---- W prep: layer = b>>3, stripe s = b&7 (cols 16s..16s+16) ----
            const int layer = b >> 3, s = b & 7;
            const float* W = layer == 0 ? W0 : layer == 1 ? W1
                          : layer == 2 ? W2 : Wr;
            {
                const int kk = t & 127, half = t >> 7;
                const float4* wr_ = (const float4*)(W + (size_t)kk * F_ + 16 * s + 8 * half);
                const float4 v0 = wr_[0], v1 = wr_[1];
                float* dst = tile + kk * 17 + 8 * half;
                dst[0] = v0.x; dst[1] = v0.y; dst[2] = v0.z; dst[3] = v0.w;
                dst[4] = v1.x; dst[5] = v1.y; dst[6] = v1.z; dst[7] = v1.w;
            }
            __syncthreads();
            {
                const int np = t & 15, kq = t >> 4;
                unsigned hw[4], lw[4];
                #pragma unroll
                for (int p = 0; p < 4; ++p) {
                    const float f0 = tile[(kq * 8 + 2 * p)     * 17 + np];
                    const float f1 = tile[(kq * 8 + 2 * p + 1) * 17 + np];
                    const unsigned short h0 = bf16_trunc(f0), h1 = bf16_trunc(f1);
                    const unsigned short l0 = bf16_trunc(f0 - bf16_tof(h0));
                    const unsigned short l1 = bf16_trunc(f1 - bf16_tof(h1));
                    hw[p] = (unsigned)h0 | ((unsigned)h1 << 16);
                    lw[p] = (unsigned)l0 | ((unsigned)l1 << 16);
                }
                const size_t base = (size_t)layer * LAYER_E
                                  + (size_t)(16 * s + np) * KP + kq * 8;
                *(int4*)(wprep + base)           = make_int4(hw[0], hw[1], hw[2], hw[3]);
                *(int4*)(wprep + base + PLANE_E) = make_int4(lw[0], lw[1], lw[2], lw[3]);
            }
            __syncthreads();
            if (t == 0) {
                __threadfence();   // push wprep to coherent point
                __hip_atomic_fetch_add(&flags->prep, 1, __ATOMIC_RELEASE,
                                       __HIP_MEMORY_SCOPE_AGENT);
            }
        }

        // ---- mean of batch b (R1-proven stream) ----
        const int fc = t & 31, cr = t >> 5;
        const float4* src = (const float4*)(emb + (size_t)b * C_ * F_);
        float4 sa = make_float4(0.f, 0.f, 0.f, 0.f);
        #pragma unroll
        for (int c = 0; c < C_ / 8; ++c) {
            const float4 v = src[(cr + c * 8) * (F_ / 4) + fc];
            sa.x += v.x; sa.y += v.y; sa.z += v.z; sa.w += v.w;
        }
        part[cr * 32 + fc] = sa;
        __syncthreads();
        if (t < 32) {
            float4 acc = part[t];
            #pragma unroll
            for (int i = 1; i < 8; ++i) {
                const float4 v = part[i * 32 + t];
                acc.x += v.x; acc.y += v.y; acc.z += v.z; acc.w += v.w;
            }
            const float inv = 1.0f / (float)C_;
            acc.x *= inv; acc.y *= inv; acc.z *= inv; acc.w *= inv;
            ((float4*)(ebar + (size_t)b * F_))[t] = acc;
        }
        __syncthreads();
        if (t == 0) {
            __threadfence();   // push ebar to coherent point
            __hip_atomic_fetch_add(&flags->cnt[b >> 5], 1, __ATOMIC_RELEASE,
                                   __HIP_MEMORY_SCOPE_AGENT);
        }
        return;
    }

    // ================= MLP ROLE =================
    const int g    = b - B_;          // 0..127
    const int row0 = g * GRP;
    unsigned short* x = (unsigned short*)smraw;   // [2 plane][GRP][KP]

    if (t == 0) {
        while (__hip_atomic_load(&flags->prep, __ATOMIC_RELAXED,
                                 __HIP_MEMORY_SCOPE_AGENT) < NPREP)
            __builtin_amdgcn_s_sleep(2);
        while (__hip_atomic_load(&flags->cnt[g], __ATOMIC_RELAXED,
                                 __HIP_MEMORY_SCOPE_AGENT) < GRP)
            __builtin_amdgcn_s_sleep(2);
        __threadfence();   // acquire: invalidate stale L2/L1 before reads
    }
    __syncthreads();

    // x: 32 rows x 128 f32 -> bf16 hi/lo planes in LDS
    {
        const float4* src = (const float4*)(ebar + (size_t)row0 * F_);
        #pragma unroll
        for (int i = 0; i < 4; ++i) {
            const int idx = t + i * 256;          // float4 slot 0..1023
            const int r = idx >> 5, c4 = idx & 31;
            const float4 v = src[idx];
            ushort4 h, lo;
            h.x = bf16_trunc(v.x); lo.x = bf16_trunc(v.x - bf16_tof(h.x));
            h.y = bf16_trunc(v.y); lo.y = bf16_trunc(v.y - bf16_tof(h.y));
            h.z = bf16_trunc(v.z); lo.z = bf16_trunc(v.z - bf16_tof(h.z));
            h.w = bf16_trunc(v.w); lo.w = bf16_trunc(v.w - bf16_tof(h.w));
            *(ushort4*)&x[(0 * GRP + r) * KP + c4 * 4] = h;
            *(ushort4*)&x[(1 * GRP + r) * KP + c4 * 4] = lo;
        }
    }
    __syncthreads();

    const int w = t >> 6, l = t & 63;
    const int q = l >> 4, c = l & 15;   // q: k-group & C-rowquad; c: A-row & B/C-col

    const float* bs[4] = {b0, b1, b2, br};
    float biasr[4][2];
    #pragma unroll
    for (int L = 0; L < 4; ++L)
        #pragma unroll
        for (int i = 0; i < 2; ++i)
            biasr[L][i] = bs[L][(2 * w + i) * 16 + c];

    #pragma unroll
    for (int L = 0; L < 4; ++L) {
        const unsigned short* wl = wprep + (size_t)L * LAYER_E;
        f32x4 acc[2][2];
        #pragma unroll
        for (int rt = 0; rt < 2; ++rt)
            #pragma unroll
            for (int i = 0; i < 2; ++i)
                acc[rt][i] = (f32x4){0.f, 0.f, 0.f, 0.f};

        #pragma unroll
        for (int kk = 0; kk < 4; ++kk) {
            const int ko = kk * 32 + q * 8;
            const short8 ah0 = *(const short8*)&x[(0 * GRP + c)      * KP + ko];
            const short8 ah1 = *(const short8*)&x[(0 * GRP + 16 + c) * KP + ko];
            const short8 al0 = *(const short8*)&x[(1 * GRP + c)      * KP + ko];
            const short8 al1 = *(const short8*)&x[(1 * GRP + 16 + c) * KP + ko];
            #pragma unroll
            for (int i = 0; i < 2; ++i) {
                const int n = (2 * w + i) * 16 + c;
                const short8 bh = *(const short8*)(wl + (size_t)n * KP + ko);
                const short8 bl = *(const short8*)(wl + PLANE_E + (size_t)n * KP + ko);
                acc[0][i] = __builtin_amdgcn_mfma_f32_16x16x32_bf16(ah0, bh, acc[0][i], 0, 0, 0);
                acc[0][i] = __builtin_amdgcn_mfma_f32_16x16x32_bf16(al0, bh, acc[0][i], 0, 0, 0);
                acc[0][i] = __builtin_amdgcn_mfma_f32_16x16x32_bf16(ah0, bl, acc[0][i], 0, 0, 0);
                acc[1][i] = __builtin_amdgcn_mfma_f32_16x16x32_bf16(ah1, bh, acc[1][i], 0, 0, 0);
                acc[1][i] = __builtin_amdgcn_mfma_f32_16x16x32_bf16(al1, bh, acc[1][i], 0, 0, 0);
                acc[1][i] = __builtin_amdgcn_mfma_f32_16x16x32_bf16(ah1, bl, acc[1][i], 0, 0, 0);
            }
        }
        __syncthreads();   // all x reads of this layer complete

        if (L < 3) {
            #pragma unroll
            for (int rt = 0; rt < 2; ++rt)
                #pragma unroll
                for (int i = 0; i < 2; ++i)
                    #pragma unroll
                    for (int j = 0; j < 4; ++j) {
                        float v = acc[rt][i][j] + biasr[L][i];
                        v = fmaxf(v, 0.f);
                        const int row = rt * 16 + q * 4 + j;
                        const int col = (2 * w + i) * 16 + c;
                        const unsigned short h = bf16_trunc(v);
                        x[(0 * GRP + row) * KP + col] = h;
                        x[(1 * GRP + row) * KP + col] = bf16_trunc(v - bf16_tof(h));
                    }
            __syncthreads();   // x' visible to all waves
        } else {
            #pragma unroll
            for (int rt = 0; rt < 2; ++rt)
                #pragma unroll
                for (int i = 0; i < 2; ++i)
                    #pragma unroll
                    for (int j = 0; j < 4; ++j)
                        out[(size_t)(row0 + rt * 16 + q * 4 + j) * F_
                            + (2 * w + i) * 16 + c] = acc[rt][i][j] + biasr[3][i];
        }
    }
}

extern "C" void kernel_launch(void* const* d_in, const int* in_sizes, int n_in,
                              void* d_out, int out_size, void* d_ws, size_t ws_size,
                              hipStream_t stream) {
    const float* emb = (const float*)d_in[0];
    const float* W0  = (const float*)d_in[1];
    const float* b0  = (const float*)d_in[2];
    const float* W1  = (const float*)d_in[3];
    const float* b1  = (const float*)d_in[4];
    const float* W2  = (const float*)d_in[5];
    const float* b2  = (const float*)d_in[6];
    const float* Wr  = (const float*)d_in[7];
    const float* br  = (const float*)d_in[8];

    char* ws = (char*)d_ws;
    float*          ebar  = (float*)ws;                               // 2 MB
    unsigned short* wprep = (unsigned short*)(ws + 2097152);          // 272 KB
    Flags*          flags = (Flags*)(ws + 2097152 + 278528);          // 516 B

    hipMemsetAsync(flags, 0, sizeof(Flags), stream);   // reset sync state每replay
    fused_all<<<B_ + NGRP, 256, 0, stream>>>(emb, W0, b0, W1, b1, W2, b2,
                                             Wr, br, ebar, wprep, flags,
                                             (float*)d_out);
}

// Round 9
// 36.967 us; speedup vs baseline: 7.2033x; 7.2033x over previous
//
#include <hip/hip_runtime.h>

#define B_ 4096
#define C_ 64
#define F_ 128
#define KP 136                       // padded K stride (bf16) -> max 2-way banks
#define PLANE_E (F_ * KP)            // 17408 u16 per plane
#define LAYER_E (2 * PLANE_E)        // hi+lo planes per layer
#define GRP 32                       // batches per MLP block
#define NGRP (B_ / GRP)              // 128 MLP blocks

typedef __attribute__((ext_vector_type(8))) short short8;
typedef __attribute__((ext_vector_type(4))) float f32x4;

__device__ __forceinline__ unsigned short bf16_trunc(float f) {
    union { float f; unsigned u; } v; v.f = f;
    return (unsigned short)(v.u >> 16);
}
__device__ __forceinline__ float bf16_tof(unsigned short h) {
    union { unsigned u; float f; } v; v.u = ((unsigned)h) << 16;
    return v.f;
}

// ---------------------------------------------------------------------------
// Kernel A (R7-proven): per-batch mean stream + W-prep folded into blocks 0-31.
// Prep: block p<32: layer=p>>3, stripe s=p&7 -> Wt[layer] rows [16s,16s+16)
// as bf16 hi/lo planes, K-innermost, K-padded to KP.
// ---------------------------------------------------------------------------
__global__ __launch_bounds__(256) void mean_prep_kernel(const float* __restrict__ emb,
                                                        float* __restrict__ ebar,
                                                        const float* __restrict__ W0,
                                                        const float* __restrict__ W1,
                                                        const float* __restrict__ W2,
                                                        const float* __restrict__ Wr,
                                                        unsigned short* __restrict__ wprep) {
    __shared__ float4 part[8][32];
    __shared__ float  tile[128 * 17];

    const int b = blockIdx.x;
    const int t = threadIdx.x;
    const int fc = t & 31;
    const int cr = t >> 5;

    // ---- stream: mean over C=64 channels of batch b ----
    {
        const float4* src = (const float4*)(emb + (size_t)b * C_ * F_);
        float4 s = make_float4(0.f, 0.f, 0.f, 0.f);
        #pragma unroll
        for (int c = 0; c < C_ / 8; ++c) {
            float4 v = src[(cr + c * 8) * (F_ / 4) + fc];
            s.x += v.x; s.y += v.y; s.z += v.z; s.w += v.w;
        }
        part[cr][fc] = s;
        __syncthreads();
        if (t < 32) {
            float4 acc = part[0][t];
            #pragma unroll
            for (int i = 1; i < 8; ++i) {
                float4 v = part[i][t];
                acc.x += v.x; acc.y += v.y; acc.z += v.z; acc.w += v.w;
            }
            const float inv = 1.0f / (float)C_;
            acc.x *= inv; acc.y *= inv; acc.z *= inv; acc.w *= inv;
            ((float4*)(ebar + (size_t)b * F_))[t] = acc;
        }
    }

    // ---- prep (32 blocks, hidden under the 4096-block stream) ----
    if (b < 32) {
        const int layer = b >> 3;
        const int s     = b & 7;
        const float* W = layer == 0 ? W0 : layer == 1 ? W1 : layer == 2 ? W2 : Wr;

        {
            const int kk = t & 127, half = t >> 7;
            const float4* wr_ = (const float4*)(W + (size_t)kk * F_ + 16 * s + 8 * half);
            const float4 v0 = wr_[0], v1 = wr_[1];
            float* dst = tile + kk * 17 + 8 * half;
            dst[0] = v0.x; dst[1] = v0.y; dst[2] = v0.z; dst[3] = v0.w;
            dst[4] = v1.x; dst[5] = v1.y; dst[6] = v1.z; dst[7] = v1.w;
        }
        __syncthreads();
        {
            const int np = t & 15, kq = t >> 4;
            unsigned hw[4], lw[4];
            #pragma unroll
            for (int p = 0; p < 4; ++p) {
                const float f0 = tile[(kq * 8 + 2 * p)     * 17 + np];
                const float f1 = tile[(kq * 8 + 2 * p + 1) * 17 + np];
                const unsigned short h0 = bf16_trunc(f0), h1 = bf16_trunc(f1);
                const unsigned short l0 = bf16_trunc(f0 - bf16_tof(h0));
                const unsigned short l1 = bf16_trunc(f1 - bf16_tof(h1));
                hw[p] = (unsigned)h0 | ((unsigned)h1 << 16);
                lw[p] = (unsigned)l0 | ((unsigned)l1 << 16);
            }
            const size_t base = (size_t)layer * LAYER_E
                              + (size_t)(16 * s + np) * KP + kq * 8;
            *(int4*)(wprep + base)           = make_int4(hw[0], hw[1], hw[2], hw[3]);
            *(int4*)(wprep + base + PLANE_E) = make_int4(lw[0], lw[1], lw[2], lw[3]);
        }
    }
}

// ---------------------------------------------------------------------------
// Kernel B: MFMA MLP, B-fragments straight from global wprep (L2-hot).
// 128 blocks x 256 thr (4 waves), GRP=32 rows/block, LDS = x only (17.4 KB).
// Split-bf16: acc += xh@Wh + xl@Wh + xh@Wl (fp32 accum), verified R7/R8.
// mfma_f32_16x16x32_bf16 maps: A row=lane&15, k=(lane>>4)*8+e;
// B col=lane&15 (same k); C col=lane&15, row=(lane>>4)*4+reg.
// ---------------------------------------------------------------------------
__global__ __launch_bounds__(256, 4) void mlp_mfma_kernel(
    const float* __restrict__ ebar,
    const unsigned short* __restrict__ wprep,
    const float* __restrict__ b0, const float* __restrict__ b1,
    const float* __restrict__ b2, const float* __restrict__ br,
    float* __restrict__ out)
{
    __shared__ unsigned short x[2 * GRP * KP];   // [plane][row][k] 17408 B

    const int t    = threadIdx.x;
    const int row0 = blockIdx.x * GRP;

    // x: 32 rows x 128 f32 -> bf16 hi/lo planes in LDS
    {
        const float4* src = (const float4*)(ebar + (size_t)row0 * F_);
        #pragma unroll
        for (int i = 0; i < 4; ++i) {
            const int idx = t + i * 256;          // float4 slot 0..1023
            const int r = idx >> 5, c4 = idx & 31;
            const float4 v = src[idx];
            ushort4 h, lo;
            h.x = bf16_trunc(v.x); lo.x = bf16_trunc(v.x - bf16_tof(h.x));
            h.y = bf16_trunc(v.y); lo.y = bf16_trunc(v.y - bf16_tof(h.y));
            h.z = bf16_trunc(v.z); lo.z = bf16_trunc(v.z - bf16_tof(h.z));
            h.w = bf16_trunc(v.w); lo.w = bf16_trunc(v.w - bf16_tof(h.w));
            *(ushort4*)&x[(0 * GRP + r) * KP + c4 * 4] = h;
            *(ushort4*)&x[(1 * GRP + r) * KP + c4 * 4] = lo;
        }
    }
    __syncthreads();

    const int w = t >> 6, l = t & 63;
    const int q = l >> 4, c = l & 15;   // q: k-group & C-rowquad; c: A-row & B/C-col

    const float* bs[4] = {b0, b1, b2, br};
    float biasr[4][2];
    #pragma unroll
    for (int L = 0; L < 4; ++L)
        #pragma unroll
        for (int i = 0; i < 2; ++i)
            biasr[L][i] = bs[L][(2 * w + i) * 16 + c];

    #pragma unroll
    for (int L = 0; L < 4; ++L) {
        const unsigned short* wl = wprep + (size_t)L * LAYER_E;
        f32x4 acc[2][2];
        #pragma unroll
        for (int rt = 0; rt < 2; ++rt)
            #pragma unroll
            for (int i = 0; i < 2; ++i)
                acc[rt][i] = (f32x4){0.f, 0.f, 0.f, 0.f};

        #pragma unroll
        for (int kk = 0; kk < 4; ++kk) {
            const int ko = kk * 32 + q * 8;
            const short8 ah0 = *(const short8*)&x[(0 * GRP + c)      * KP + ko];
            const short8 ah1 = *(const short8*)&x[(0 * GRP + 16 + c) * KP + ko];
            const short8 al0 = *(const short8*)&x[(1 * GRP + c)      * KP + ko];
            const short8 al1 = *(const short8*)&x[(1 * GRP + 16 + c) * KP + ko];
            #pragma unroll
            for (int i = 0; i < 2; ++i) {
                const int n = (2 * w + i) * 16 + c;
                const short8 bh = *(const short8*)(wl + (size_t)n * KP + ko);
                const short8 bl = *(const short8*)(wl + PLANE_E + (size_t)n * KP + ko);
                acc[0][i] = __builtin_amdgcn_mfma_f32_16x16x32_bf16(ah0, bh, acc[0][i], 0, 0, 0);
                acc[0][i] = __builtin_amdgcn_mfma_f32_16x16x32_bf16(al0, bh, acc[0][i], 0, 0, 0);
                acc[0][i] = __builtin_amdgcn_mfma_f32_16x16x32_bf16(ah0, bl, acc[0][i], 0, 0, 0);
                acc[1][i] = __builtin_amdgcn_mfma_f32_16x16x32_bf16(ah1, bh, acc[1][i], 0, 0, 0);
                acc[1][i] = __builtin_amdgcn_mfma_f32_16x16x32_bf16(al1, bh, acc[1][i], 0, 0, 0);
                acc[1][i] = __builtin_amdgcn_mfma_f32_16x16x32_bf16(ah1, bl, acc[1][i], 0, 0, 0);
            }
        }
        __syncthreads();   // all x reads of this layer complete

        if (L < 3) {
            #pragma unroll
            for (int rt = 0; rt < 2; ++rt)
                #pragma unroll
                for (int i = 0; i < 2; ++i)
                    #pragma unroll
                    for (int j = 0; j < 4; ++j) {
                        float v = acc[rt][i][j] + biasr[L][i];
                        v = fmaxf(v, 0.f);
                        const int row = rt * 16 + q * 4 + j;
                        const int col = (2 * w + i) * 16 + c;
                        const unsigned short h = bf16_trunc(v);
                        x[(0 * GRP + row) * KP + col] = h;
                        x[(1 * GRP + row) * KP + col] = bf16_trunc(v - bf16_tof(h));
                    }
            __syncthreads();   // x' visible to all waves
        } else {
            #pragma unroll
            for (int rt = 0; rt < 2; ++rt)
                #pragma unroll
                for (int i = 0; i < 2; ++i)
                    #pragma unroll
                    for (int j = 0; j < 4; ++j)
                        out[(size_t)(row0 + rt * 16 + q * 4 + j) * F_
                            + (2 * w + i) * 16 + c] = acc[rt][i][j] + biasr[3][i];
        }
    }
}

extern "C" void kernel_launch(void* const* d_in, const int* in_sizes, int n_in,
                              void* d_out, int out_size, void* d_ws, size_t ws_size,
                              hipStream_t stream) {
    const float* emb = (const float*)d_in[0];
    const float* W0  = (const float*)d_in[1];
    const float* b0  = (const float*)d_in[2];
    const float* W1  = (const float*)d_in[3];
    const float* b1  = (const float*)d_in[4];
    const float* W2  = (const float*)d_in[5];
    const float* b2  = (const float*)d_in[6];
    const float* Wr  = (const float*)d_in[7];
    const float* br  = (const float*)d_in[8];

    float*          ebar  = (float*)d_ws;                             // 2 MB
    unsigned short* wprep = (unsigned short*)((char*)d_ws + 2097152); // 272 KB

    mean_prep_kernel<<<B_, 256, 0, stream>>>(emb, ebar, W0, W1, W2, Wr, wprep);
    mlp_mfma_kernel<<<NGRP, 256, 0, stream>>>(ebar, wprep, b0, b1, b2, br,
                                              (float*)d_out);
}

// Round 10
// 33.623 us; speedup vs baseline: 7.9197x; 1.0995x over previous
//
#include <hip/hip_runtime.h>

#define B_ 4096
#define C_ 64
#define F_ 128
#define KP 136                 // padded K stride (bf16) for the x tile only
#define GRP 32                 // batches per MLP block
#define NBLK (B_ / GRP)        // 128 MLP blocks
#define WSLICE 8192            // u16 per (wave, layer): 16 frags x 512
#define WLAYER 32768           // u16 per layer: 4 wave-slices (64 KB)

typedef __attribute__((address_space(3))) unsigned int lds_u32;
typedef __attribute__((address_space(1))) unsigned int glb_u32;
typedef __attribute__((ext_vector_type(8))) short short8;
typedef __attribute__((ext_vector_type(4))) float f32x4;

__device__ __forceinline__ unsigned short bf16_trunc(float f) {
    union { float f; unsigned u; } v; v.f = f;
    return (unsigned short)(v.u >> 16);
}
__device__ __forceinline__ float bf16_tof(unsigned short h) {
    union { unsigned u; float f; } v; v.u = ((unsigned)h) << 16;
    return v.f;
}

// ---------------------------------------------------------------------------
// Kernel A: per-batch mean stream (R1-proven) + W-prep in blocks 0-31.
// Prep now writes wprep FRAGMENT-MAJOR: [layer][wave][frag = iloc*8+kk*2+pl]
// [lane][e] — exactly the MFMA B-fragment consumption order, so the MLP's
// stage is linear and its ds_reads are contiguous conflict-free b128.
// Block s covers n-tile s (cols 16s..16s+16) -> wave w=s>>1, iloc=s&1.
// ---------------------------------------------------------------------------
__global__ __launch_bounds__(256) void mean_prep_kernel(const float* __restrict__ emb,
                                                        float* __restrict__ ebar,
                                                        const float* __restrict__ W0,
                                                        const float* __restrict__ W1,
                                                        const float* __restrict__ W2,
                                                        const float* __restrict__ Wr,
                                                        unsigned short* __restrict__ wprep) {
    __shared__ float4 part[8][32];
    __shared__ float  tile[128 * 17];

    const int b = blockIdx.x;
    const int t = threadIdx.x;
    const int fc = t & 31;
    const int cr = t >> 5;

    // ---- stream: mean over C=64 channels of batch b ----
    {
        const float4* src = (const float4*)(emb + (size_t)b * C_ * F_);
        float4 s = make_float4(0.f, 0.f, 0.f, 0.f);
        #pragma unroll
        for (int c = 0; c < C_ / 8; ++c) {
            float4 v = src[(cr + c * 8) * (F_ / 4) + fc];
            s.x += v.x; s.y += v.y; s.z += v.z; s.w += v.w;
        }
        part[cr][fc] = s;
        __syncthreads();
        if (t < 32) {
            float4 acc = part[0][t];
            #pragma unroll
            for (int i = 1; i < 8; ++i) {
                float4 v = part[i][t];
                acc.x += v.x; acc.y += v.y; acc.z += v.z; acc.w += v.w;
            }
            const float inv = 1.0f / (float)C_;
            acc.x *= inv; acc.y *= inv; acc.z *= inv; acc.w *= inv;
            ((float4*)(ebar + (size_t)b * F_))[t] = acc;
        }
    }

    // ---- prep (32 blocks, hidden under the 4096-block stream) ----
    if (b < 32) {
        const int layer = b >> 3;
        const int s     = b & 7;
        const float* W = layer == 0 ? W0 : layer == 1 ? W1 : layer == 2 ? W2 : Wr;

        {   // load W[k][16s..16s+16) for all k into tile[k][c]
            const int kk = t & 127, half = t >> 7;
            const float4* wr_ = (const float4*)(W + (size_t)kk * F_ + 16 * s + 8 * half);
            const float4 v0 = wr_[0], v1 = wr_[1];
            float* dst = tile + kk * 17 + 8 * half;
            dst[0] = v0.x; dst[1] = v0.y; dst[2] = v0.z; dst[3] = v0.w;
            dst[4] = v1.x; dst[5] = v1.y; dst[6] = v1.z; dst[7] = v1.w;
        }
        __syncthreads();
        {   // fragment-major writeout
            const int ln = t & 63;
            const int c = ln & 15, q = ln >> 4;
            const int kkpl_base = t >> 6;           // 0..3
            #pragma unroll
            for (int rep = 0; rep < 2; ++rep) {
                const int kkpl = kkpl_base + rep * 4;   // 0..7
                const int kk = kkpl >> 1, pl = kkpl & 1;
                unsigned wd[4];
                #pragma unroll
                for (int p = 0; p < 4; ++p) {
                    unsigned short u[2];
                    #pragma unroll
                    for (int h2 = 0; h2 < 2; ++h2) {
                        const int e = 2 * p + h2;
                        const float f = tile[(kk * 32 + q * 8 + e) * 17 + c];
                        const unsigned short hi = bf16_trunc(f);
                        u[h2] = (pl == 0) ? hi : bf16_trunc(f - bf16_tof(hi));
                    }
                    wd[p] = (unsigned)u[0] | ((unsigned)u[1] << 16);
                }
                const size_t dst = ((size_t)(layer * 4 + (s >> 1)) * 16
                                    + (size_t)((s & 1) * 8 + kkpl)) * 512 + ln * 8;
                *(int4*)(wprep + dst) = make_int4(wd[0], wd[1], wd[2], wd[3]);
            }
        }
    }
}

// Async stage of one layer's W (64 KB, frag-major, contiguous) into LDS.
// 16 iters x 256 thr x 16 B; lane-linear dest (HW requirement).
__device__ __forceinline__ void stage_w(const unsigned short* __restrict__ src,
                                        unsigned short* dst, int t) {
    #pragma unroll
    for (int i = 0; i < 16; ++i) {
        const int e = i * 2048 + t * 8;   // u16; bytes = i*4096 + t*16
        __builtin_amdgcn_global_load_lds((const glb_u32*)(src + e),
                                         (lds_u32*)(dst + e), 16, 0, 0);
    }
}

// ---------------------------------------------------------------------------
// Kernel B: MFMA MLP. 128 blocks x 256 thr, GRP=32 rows/block.
// W LDS-staged (async, double-buffered, R7-proven schedule) in frag-major
// layout -> B ds_reads are contiguous b128 (conflict-free).
// Split-bf16 (R7/R9-proven): acc += xh@Wh + xl@Wh + xh@Wl, fp32 accum.
// ---------------------------------------------------------------------------
__global__ __launch_bounds__(256, 1) void mlp_mfma_kernel(
    const float* __restrict__ ebar,
    const unsigned short* __restrict__ wprep,
    const float* __restrict__ b0, const float* __restrict__ b1,
    const float* __restrict__ b2, const float* __restrict__ br,
    float* __restrict__ out)
{
    __shared__ unsigned short wb[2][WLAYER];     // 128 KB
    __shared__ unsigned short x[2 * GRP * KP];   // 17408 B  (total 145.4 KB)

    const int t    = threadIdx.x;
    const int row0 = blockIdx.x * GRP;

    stage_w(wprep, wb[0], t);   // W0, overlaps x prologue

    // x: 32 rows x 128 f32 -> bf16 hi/lo planes in LDS
    {
        const float4* src = (const float4*)(ebar + (size_t)row0 * F_);
        #pragma unroll
        for (int i = 0; i < 4; ++i) {
            const int idx = t + i * 256;
            const int r = idx >> 5, c4 = idx & 31;
            const float4 v = src[idx];
            ushort4 h, lo;
            h.x = bf16_trunc(v.x); lo.x = bf16_trunc(v.x - bf16_tof(h.x));
            h.y = bf16_trunc(v.y); lo.y = bf16_trunc(v.y - bf16_tof(h.y));
            h.z = bf16_trunc(v.z); lo.z = bf16_trunc(v.z - bf16_tof(h.z));
            h.w = bf16_trunc(v.w); lo.w = bf16_trunc(v.w - bf16_tof(h.w));
            *(ushort4*)&x[(0 * GRP + r) * KP + c4 * 4] = h;
            *(ushort4*)&x[(1 * GRP + r) * KP + c4 * 4] = lo;
        }
    }
    __syncthreads();   // x visible; W0 staged (barrier drains vmcnt)

    const int w = t >> 6, l = t & 63;
    const int q = l >> 4, c = l & 15;

    const float* bs[4] = {b0, b1, b2, br};
    float biasr[4][2];
    #pragma unroll
    for (int L = 0; L < 4; ++L)
        #pragma unroll
        for (int i = 0; i < 2; ++i)
            biasr[L][i] = bs[L][(2 * w + i) * 16 + c];

    #pragma unroll
    for (int L = 0; L < 4; ++L) {
        if (L < 3) stage_w(wprep + (size_t)(L + 1) * WLAYER, wb[(L + 1) & 1], t);
        const unsigned short* ws = wb[L & 1] + w * WSLICE;

        f32x4 acc[2][2];
        #pragma unroll
        for (int rt = 0; rt < 2; ++rt)
            #pragma unroll
            for (int i = 0; i < 2; ++i)
                acc[rt][i] = (f32x4){0.f, 0.f, 0.f, 0.f};

        #pragma unroll
        for (int kk = 0; kk < 4; ++kk) {
            const int ko = kk * 32 + q * 8;
            const short8 ah0 = *(const short8*)&x[(0 * GRP + c)      * KP + ko];
            const short8 ah1 = *(const short8*)&x[(0 * GRP + 16 + c) * KP + ko];
            const short8 al0 = *(const short8*)&x[(1 * GRP + c)      * KP + ko];
            const short8 al1 = *(const short8*)&x[(1 * GRP + 16 + c) * KP + ko];
            #pragma unroll
            for (int i = 0; i < 2; ++i) {
                const short8 bh = *(const short8*)&ws[(i * 8 + kk * 2 + 0) * 512 + l * 8];
                const short8 bl = *(const short8*)&ws[(i * 8 + kk * 2 + 1) * 512 + l * 8];
                acc[0][i] = __builtin_amdgcn_mfma_f32_16x16x32_bf16(ah0, bh, acc[0][i], 0, 0, 0);
                acc[0][i] = __builtin_amdgcn_mfma_f32_16x16x32_bf16(al0, bh, acc[0][i], 0, 0, 0);
                acc[0][i] = __builtin_amdgcn_mfma_f32_16x16x32_bf16(ah0, bl, acc[0][i], 0, 0, 0);
                acc[1][i] = __builtin_amdgcn_mfma_f32_16x16x32_bf16(ah1, bh, acc[1][i], 0, 0, 0);
                acc[1][i] = __builtin_amdgcn_mfma_f32_16x16x32_bf16(al1, bh, acc[1][i], 0, 0, 0);
                acc[1][i] = __builtin_amdgcn_mfma_f32_16x16x32_bf16(ah1, bl, acc[1][i], 0, 0, 0);
            }
        }
        __syncthreads();   // x reads done; W[L+1] stage drained

        if (L < 3) {
            #pragma unroll
            for (int rt = 0; rt < 2; ++rt)
                #pragma unroll
                for (int i = 0; i < 2; ++i)
                    #pragma unroll
                    for (int j = 0; j < 4; ++j) {
                        float v = acc[rt][i][j] + biasr[L][i];
                        v = fmaxf(v, 0.f);
                        const int row = rt * 16 + q * 4 + j;
                        const int col = (2 * w + i) * 16 + c;
                        const unsigned short h = bf16_trunc(v);
                        x[(0 * GRP + row) * KP + col] = h;
                        x[(1 * GRP + row) * KP + col] = bf16_trunc(v - bf16_tof(h));
                    }
            __syncthreads();   // x' visible to all waves
        } else {
            #pragma unroll
            for (int rt = 0; rt < 2; ++rt)
                #pragma unroll
                for (int i = 0; i < 2; ++i)
                    #pragma unroll
                    for (int j = 0; j < 4; ++j)
                        out[(size_t)(row0 + rt * 16 + q * 4 + j) * F_
                            + (2 * w + i) * 16 + c] = acc[rt][i][j] + biasr[3][i];
        }
    }
}

extern "C" void kernel_launch(void* const* d_in, const int* in_sizes, int n_in,
                              void* d_out, int out_size, void* d_ws, size_t ws_size,
                              hipStream_t stream) {
    const float* emb = (const float*)d_in[0];
    const float* W0  = (const float*)d_in[1];
    const float* b0  = (const float*)d_in[2];
    const float* W1  = (const float*)d_in[3];
    const float* b1  = (const float*)d_in[4];
    const float* W2  = (const float*)d_in[5];
    const float* b2  = (const float*)d_in[6];
    const float* Wr  = (const float*)d_in[7];
    const float* br  = (const float*)d_in[8];

    float*          ebar  = (float*)d_ws;                             // 2 MB
    unsigned short* wprep = (unsigned short*)((char*)d_ws + 2097152); // 256 KB

    mean_prep_kernel<<<B_, 256, 0, stream>>>(emb, ebar, W0, W1, W2, Wr, wprep);
    mlp_mfma_kernel<<<NBLK, 256, 0, stream>>>(ebar, wprep, b0, b1, b2, br,
                                              (float*)d_out);
}